// Round 2
// baseline (767.793 us; speedup 1.0000x reference)
//
#include <hip/hip_runtime.h>
#include <math.h>

#define DIM   2048
#define NH    16
#define HD    128
#define BB    2
#define SS    2048
#define MTOT  4096   // BB*SS

typedef unsigned short u16;
typedef short bf16x8 __attribute__((ext_vector_type(8)));
typedef float f32x4  __attribute__((ext_vector_type(4)));

typedef const void __attribute__((address_space(1)))* gas_ptr;
typedef void __attribute__((address_space(3)))* las_ptr;

__device__ __forceinline__ u16 f2bf(float f){
  union { float f; unsigned u; } v; v.f = f;
  unsigned r = v.u + 0x7FFFu + ((v.u >> 16) & 1u);
  return (u16)(r >> 16);
}
__device__ __forceinline__ float bf2f(u16 h){
  union { unsigned u; float f; } v; v.u = ((unsigned)h) << 16;
  return v.f;
}

// ---------------- fp32 -> bf16 conversion (4 elems/thread) ----------------
__global__ __launch_bounds__(256) void cvt_kernel(const float* __restrict__ in,
                                                  u16* __restrict__ out, int n4){
  int i = blockIdx.x * blockDim.x + threadIdx.x;
  if (i >= n4) return;
  float4 v = ((const float4*)in)[i];
  ushort4 o;
  o.x = f2bf(v.x); o.y = f2bf(v.y); o.z = f2bf(v.z); o.w = f2bf(v.w);
  ((ushort4*)out)[i] = o;
}

// ---------------- GEMM  C = A * B^T  (A: MxK, B: NxK, both bf16 row-major) ----------------
// 128x128 tile, BK=32, 4 waves (2x2), each wave 64x64 = 4x4 frags of 16x16x32.
template<bool STORE_BF16>
__global__ __launch_bounds__(256) void gemm_bt(
    const u16* __restrict__ A,
    const u16* __restrict__ B0, const u16* __restrict__ B1, const u16* __restrict__ B2,
    void* __restrict__ C0, void* __restrict__ C1, void* __restrict__ C2,
    int M, int N, int K)
{
  const u16* Bm = (blockIdx.z == 0) ? B0 : (blockIdx.z == 1 ? B1 : B2);
  void* Cm      = (blockIdx.z == 0) ? C0 : (blockIdx.z == 1 ? C1 : C2);

  __shared__ __align__(16) u16 Alds[128 * 32];
  __shared__ __align__(16) u16 Blds[128 * 32];

  const int tid  = threadIdx.x;
  const int lane = tid & 63;
  const int wave = tid >> 6;
  const int wr   = wave >> 1;       // wave row (0..1)
  const int wc   = wave & 1;        // wave col (0..1)
  const int lg   = lane >> 4;       // k-group 0..3
  const int lr   = lane & 15;
  const int m0   = blockIdx.y * 128;
  const int n0   = blockIdx.x * 128;

  f32x4 acc[4][4];
#pragma unroll
  for (int m = 0; m < 4; ++m)
#pragma unroll
    for (int n = 0; n < 4; ++n) acc[m][n] = (f32x4)0.0f;

  for (int k0 = 0; k0 < K; k0 += 32) {
    __syncthreads();   // all waves done reading previous tile
#pragma unroll
    for (int it = 0; it < 2; ++it) {
      int chunk = it * 256 + tid;       // 0..511 : 16B chunks of the 128x32 tile
      int row   = chunk >> 2;           // 4 chunks (64B) per row
      int cc    = chunk & 3;
      const u16* ga = A  + (size_t)(m0 + row) * K + k0 + cc * 8;
      const u16* gb = Bm + (size_t)(n0 + row) * K + k0 + cc * 8;
      char* la = (char*)Alds + (it * 256 + wave * 64) * 16;  // wave-uniform base
      char* lb = (char*)Blds + (it * 256 + wave * 64) * 16;
      __builtin_amdgcn_global_load_lds((gas_ptr)ga, (las_ptr)la, 16, 0, 0);
      __builtin_amdgcn_global_load_lds((gas_ptr)gb, (las_ptr)lb, 16, 0, 0);
    }
    __syncthreads();   // staging visible

    bf16x8 a[4], b[4];
#pragma unroll
    for (int m = 0; m < 4; ++m)
      a[m] = *(const bf16x8*)(Alds + (wr * 64 + m * 16 + lr) * 32 + lg * 8);
#pragma unroll
    for (int n = 0; n < 4; ++n)
      b[n] = *(const bf16x8*)(Blds + (wc * 64 + n * 16 + lr) * 32 + lg * 8);
#pragma unroll
    for (int m = 0; m < 4; ++m)
#pragma unroll
      for (int n = 0; n < 4; ++n)
        acc[m][n] = __builtin_amdgcn_mfma_f32_16x16x32_bf16(a[m], b[n], acc[m][n], 0, 0, 0);
  }

#pragma unroll
  for (int m = 0; m < 4; ++m) {
    int grow = m0 + wr * 64 + m * 16 + lg * 4;
#pragma unroll
    for (int n = 0; n < 4; ++n) {
      int gcol = n0 + wc * 64 + n * 16 + lr;
#pragma unroll
      for (int r = 0; r < 4; ++r) {
        float val = acc[m][n][r];
        if (STORE_BF16) ((u16*)Cm)[(size_t)(grow + r) * N + gcol]   = f2bf(val);
        else            ((float*)Cm)[(size_t)(grow + r) * N + gcol] = val;
      }
    }
  }
}

// ---------------- RoPE (in-place on Q and K, bf16) ----------------
// out[j]    = x[j]*cos(t*f_j)    - x[2j+1]*sin(t*f_j)      (j < 64)
// out[j+64] = x[j+64]*cos(t*f_j) + x[2j]  *sin(t*f_j)
// One wave owns one (b,s,h) head vector; cross-lane via shfl (no mem race).
__global__ __launch_bounds__(256) void rope_kernel(u16* __restrict__ Q, u16* __restrict__ Kt){
  int gid  = blockIdx.x * 4 + (threadIdx.x >> 6);  // head index 0..65535
  int lane = threadIdx.x & 63;                     // j
  int h = gid & (NH - 1);
  int s = (gid >> 4) & (SS - 1);
  int b = gid >> 15;
  size_t base = ((size_t)(b * SS + s)) * DIM + (size_t)h * HD;

  // angle = s * 10000^(-j/64) = s * exp(-j * ln(10000)/64)
  float ang = (float)s * __expf(-(float)lane * 0.14391156831212787f);
  float c, sn;
  sincosf(ang, &sn, &c);
  int jh = lane >> 1;
  int par = lane & 1;

  // Q
  unsigned pq = *(const unsigned*)(Q + base + 2 * lane);
  float qe = bf2f((u16)(pq & 0xffff)), qo = bf2f((u16)(pq >> 16));
  float qa  = __shfl(qe, jh),      qb  = __shfl(qo, jh);
  float qa2 = __shfl(qe, 32 + jh), qb2 = __shfl(qo, 32 + jh);
  float qxj   = par ? qb  : qa;
  float qxj64 = par ? qb2 : qa2;
  u16 q_lo = f2bf(qxj   * c - qo * sn);
  u16 q_hi = f2bf(qxj64 * c + qe * sn);

  // K
  unsigned pk = *(const unsigned*)(Kt + base + 2 * lane);
  float ke = bf2f((u16)(pk & 0xffff)), ko = bf2f((u16)(pk >> 16));
  float ka  = __shfl(ke, jh),      kb  = __shfl(ko, jh);
  float ka2 = __shfl(ke, 32 + jh), kb2 = __shfl(ko, 32 + jh);
  float kxj   = par ? kb  : ka;
  float kxj64 = par ? kb2 : ka2;
  u16 k_lo = f2bf(kxj   * c - ko * sn);
  u16 k_hi = f2bf(kxj64 * c + ke * sn);

  Q [base + lane] = q_lo;  Q [base + 64 + lane] = q_hi;
  Kt[base + lane] = k_lo;  Kt[base + 64 + lane] = k_hi;
}

// ---------------- Flash attention (causal) ----------------
// grid: (S/64 q-tiles, B*H). 4 waves x 16 q-rows. KV tile 64. D=128.
#define SCALE 0.08838834764831845f

__global__ __launch_bounds__(256) void attn_kernel(
    const u16* __restrict__ Q, const u16* __restrict__ Kg, const u16* __restrict__ V,
    u16* __restrict__ AO)
{
  __shared__ __align__(16) u16 Klds[64 * 128];
  __shared__ __align__(16) u16 Vlds[128 * 64];     // transposed: [d][kv]
  __shared__ __align__(16) u16 Plds[4][16 * 64];

  const int tid  = threadIdx.x;
  const int lane = tid & 63;
  const int w    = tid >> 6;
  const int lg   = lane >> 4;
  const int lr   = lane & 15;
  const int q0   = blockIdx.x * 64;
  const int bh   = blockIdx.y;
  const int b    = bh >> 4, h = bh & 15;
  const size_t headoff = (size_t)b * SS * DIM + (size_t)h * HD;

  // Q fragments: rows q0 + w*16 + lr
  bf16x8 qf[4];
  {
    const u16* qrow = Q + headoff + (size_t)(q0 + w * 16 + lr) * DIM;
#pragma unroll
    for (int kf = 0; kf < 4; ++kf)
      qf[kf] = *(const bf16x8*)(qrow + kf * 32 + lg * 8);
  }

  f32x4 o_acc[8];
#pragma unroll
  for (int nf = 0; nf < 8; ++nf) o_acc[nf] = (f32x4)0.0f;
  float mrow[4] = {-INFINITY, -INFINITY, -INFINITY, -INFINITY};
  float lrow[4] = {0.f, 0.f, 0.f, 0.f};

  const int ntiles = q0 / 64 + 1;
  for (int tile = 0; tile < ntiles; ++tile) {
    const int kv0 = tile * 64;
    __syncthreads();
    // stage K tile [64][128], swizzled
#pragma unroll
    for (int it = 0; it < 4; ++it) {
      int chunk = it * 256 + tid;       // 1024 16B chunks
      int r  = chunk >> 4;
      int cc = chunk & 15;
      uint4 kv = *(const uint4*)(Kg + headoff + (size_t)(kv0 + r) * DIM + cc * 8);
      int byteoff = (r * 256 + cc * 16) ^ ((r & 7) << 4);
      *(uint4*)((char*)Klds + byteoff) = kv;
    }
    // stage V transposed [128][64], swizzled (coalesced uint4 loads)
#pragma unroll
    for (int it = 0; it < 4; ++it) {
      int chunk = it * 256 + tid;       // 1024 chunks of 8 elems
      int r  = chunk >> 4;              // kv row
      int c8 = chunk & 15;              // 8-elem group in d
      uint4 vv = *(const uint4*)(V + headoff + (size_t)(kv0 + r) * DIM + c8 * 8);
      const u16* pv = (const u16*)&vv;
#pragma unroll
      for (int j = 0; j < 8; ++j) {
        int cdim = c8 * 8 + j;
        int byteoff = (cdim * 128 + r * 2) ^ ((cdim & 7) << 4);
        *(u16*)((char*)Vlds + byteoff) = pv[j];
      }
    }
    __syncthreads();

    // S = Q K^T for this wave's 16 rows x 64 cols
    f32x4 sacc[4];
#pragma unroll
    for (int sf = 0; sf < 4; ++sf) {
      sacc[sf] = (f32x4)0.0f;
      int row = sf * 16 + lr;
      int swz = (row & 7) << 4;
#pragma unroll
      for (int kf = 0; kf < 4; ++kf) {
        bf16x8 kfrag = *(const bf16x8*)((char*)Klds + ((row * 256 + kf * 64 + lg * 16) ^ swz));
        sacc[sf] = __builtin_amdgcn_mfma_f32_16x16x32_bf16(qf[kf], kfrag, sacc[sf], 0, 0, 0);
      }
    }

    // online softmax
    const bool diag = (kv0 == q0);
    float p[4][4];
    float mt[4];
#pragma unroll
    for (int r = 0; r < 4; ++r) {
      int qrow = q0 + w * 16 + lg * 4 + r;
      float mx = -INFINITY;
#pragma unroll
      for (int sf = 0; sf < 4; ++sf) {
        float v = sacc[sf][r] * SCALE;
        if (diag && (kv0 + sf * 16 + lr > qrow)) v = -INFINITY;
        p[sf][r] = v;
        mx = fmaxf(mx, v);
      }
      mx = fmaxf(mx, __shfl_xor(mx, 1));
      mx = fmaxf(mx, __shfl_xor(mx, 2));
      mx = fmaxf(mx, __shfl_xor(mx, 4));
      mx = fmaxf(mx, __shfl_xor(mx, 8));
      mt[r] = mx;
    }
    float alpha[4];
#pragma unroll
    for (int r = 0; r < 4; ++r) {
      float mn = fmaxf(mrow[r], mt[r]);
      alpha[r] = __expf(mrow[r] - mn);
      mrow[r] = mn;
    }
#pragma unroll
    for (int r = 0; r < 4; ++r) {
      float s = 0.f;
#pragma unroll
      for (int sf = 0; sf < 4; ++sf) {
        float pv = __expf(p[sf][r] - mrow[r]);
        p[sf][r] = pv;
        s += pv;
      }
      s += __shfl_xor(s, 1);
      s += __shfl_xor(s, 2);
      s += __shfl_xor(s, 4);
      s += __shfl_xor(s, 8);
      lrow[r] = lrow[r] * alpha[r] + s;
    }
#pragma unroll
    for (int nf = 0; nf < 8; ++nf)
#pragma unroll
      for (int r = 0; r < 4; ++r) o_acc[nf][r] *= alpha[r];

    // write P (bf16) to per-wave LDS, swizzled
#pragma unroll
    for (int sf = 0; sf < 4; ++sf)
#pragma unroll
      for (int r = 0; r < 4; ++r) {
        int row = lg * 4 + r, col = sf * 16 + lr;
        int byteoff = (row * 128 + col * 2) ^ ((row & 7) << 4);
        *(u16*)((char*)Plds[w] + byteoff) = f2bf(p[sf][r]);
      }

    // O += P V
#pragma unroll
    for (int ks = 0; ks < 2; ++ks) {
      bf16x8 pfrag = *(const bf16x8*)((char*)Plds[w] + ((lr * 128 + ks * 64 + lg * 16) ^ ((lr & 7) << 4)));
#pragma unroll
      for (int nf = 0; nf < 8; ++nf) {
        int vrow = nf * 16 + lr;
        bf16x8 vfrag = *(const bf16x8*)((char*)Vlds + ((vrow * 128 + ks * 64 + lg * 16) ^ ((vrow & 7) << 4)));
        o_acc[nf] = __builtin_amdgcn_mfma_f32_16x16x32_bf16(pfrag, vfrag, o_acc[nf], 0, 0, 0);
      }
    }
  }

  float inv[4];
#pragma unroll
  for (int r = 0; r < 4; ++r) inv[r] = 1.0f / lrow[r];
#pragma unroll
  for (int nf = 0; nf < 8; ++nf)
#pragma unroll
    for (int r = 0; r < 4; ++r) {
      int grow = q0 + w * 16 + lg * 4 + r;
      int col  = nf * 16 + lr;
      AO[(size_t)(b * SS + grow) * DIM + h * HD + col] = f2bf(o_acc[nf][r] * inv[r]);
    }
}

// ---------------- launch ----------------
extern "C" void kernel_launch(void* const* d_in, const int* in_sizes, int n_in,
                              void* d_out, int out_size, void* d_ws, size_t ws_size,
                              hipStream_t stream)
{
  const float* x  = (const float*)d_in[0];
  const float* Wq = (const float*)d_in[1];
  const float* Wk = (const float*)d_in[2];
  const float* Wv = (const float*)d_in[3];
  const float* Wo = (const float*)d_in[4];
  float* out = (float*)d_out;

  char* ws = (char*)d_ws;
  const size_t XB_BYTES = (size_t)MTOT * DIM * 2;   // 16 MB
  const size_t W_BYTES  = (size_t)DIM * DIM * 2;    // 8 MB
  u16* xb = (u16*)ws;                                // x bf16; later reused as AO
  u16* w0 = (u16*)(ws + XB_BYTES);                   // Wq, later Wo
  u16* w1 = (u16*)(ws + XB_BYTES + W_BYTES);
  u16* w2 = (u16*)(ws + XB_BYTES + 2 * W_BYTES);
  u16* Qb = (u16*)(ws + XB_BYTES + 3 * W_BYTES);
  u16* Kb = Qb + (size_t)MTOT * DIM;
  u16* Vb = Kb + (size_t)MTOT * DIM;
  u16* AO = xb;

  cvt_kernel<<<8192, 256, 0, stream>>>(x,  xb, 2097152);
  cvt_kernel<<<4096, 256, 0, stream>>>(Wq, w0, 1048576);
  cvt_kernel<<<4096, 256, 0, stream>>>(Wk, w1, 1048576);
  cvt_kernel<<<4096, 256, 0, stream>>>(Wv, w2, 1048576);

  gemm_bt<true><<<dim3(16, 32, 3), 256, 0, stream>>>(xb, w0, w1, w2,
                                                     (void*)Qb, (void*)Kb, (void*)Vb,
                                                     MTOT, DIM, DIM);

  rope_kernel<<<16384, 256, 0, stream>>>(Qb, Kb);

  cvt_kernel<<<4096, 256, 0, stream>>>(Wo, w0, 1048576);  // Wq slot no longer needed

  attn_kernel<<<dim3(32, 32), 256, 0, stream>>>(Qb, Kb, Vb, AO);

  gemm_bt<false><<<dim3(16, 32, 1), 256, 0, stream>>>(AO, w0, w0, w0,
                                                      (void*)out, (void*)out, (void*)out,
                                                      MTOT, DIM, DIM);
}

// Round 3
// 448.455 us; speedup vs baseline: 1.7121x; 1.7121x over previous
//
#include <hip/hip_runtime.h>
#include <math.h>

#define DIM   2048
#define NH    16
#define HD    128
#define BB    2
#define SS    2048
#define MTOT  4096   // BB*SS

typedef unsigned short u16;
typedef short bf16x8 __attribute__((ext_vector_type(8)));
typedef float f32x4  __attribute__((ext_vector_type(4)));

typedef const void __attribute__((address_space(1)))* gas_ptr;
typedef void __attribute__((address_space(3)))* las_ptr;

__device__ __forceinline__ u16 f2bf(float f){
  union { float f; unsigned u; } v; v.f = f;
  unsigned r = v.u + 0x7FFFu + ((v.u >> 16) & 1u);
  return (u16)(r >> 16);
}
__device__ __forceinline__ float bf2f(u16 h){
  union { unsigned u; float f; } v; v.u = ((unsigned)h) << 16;
  return v.f;
}

// ---------------- fp32 -> bf16 conversion (4 elems/thread) ----------------
__global__ __launch_bounds__(256) void cvt_kernel(const float* __restrict__ in,
                                                  u16* __restrict__ out, int n4){
  int i = blockIdx.x * blockDim.x + threadIdx.x;
  if (i >= n4) return;
  float4 v = ((const float4*)in)[i];
  ushort4 o;
  o.x = f2bf(v.x); o.y = f2bf(v.y); o.z = f2bf(v.z); o.w = f2bf(v.w);
  ((ushort4*)out)[i] = o;
}

// ---------------- GEMM  C = A * B^T  (A: MxK, B: NxK, both bf16 row-major) ----------------
template<bool STORE_BF16>
__global__ __launch_bounds__(256) void gemm_bt(
    const u16* __restrict__ A,
    const u16* __restrict__ B0, const u16* __restrict__ B1, const u16* __restrict__ B2,
    void* __restrict__ C0, void* __restrict__ C1, void* __restrict__ C2,
    int M, int N, int K)
{
  const u16* Bm = (blockIdx.z == 0) ? B0 : (blockIdx.z == 1 ? B1 : B2);
  void* Cm      = (blockIdx.z == 0) ? C0 : (blockIdx.z == 1 ? C1 : C2);

  __shared__ __align__(16) u16 Alds[128 * 32];
  __shared__ __align__(16) u16 Blds[128 * 32];

  const int tid  = threadIdx.x;
  const int lane = tid & 63;
  const int wave = tid >> 6;
  const int wr   = wave >> 1;
  const int wc   = wave & 1;
  const int lg   = lane >> 4;
  const int lr   = lane & 15;
  const int m0   = blockIdx.y * 128;
  const int n0   = blockIdx.x * 128;

  f32x4 acc[4][4];
#pragma unroll
  for (int m = 0; m < 4; ++m)
#pragma unroll
    for (int n = 0; n < 4; ++n) acc[m][n] = (f32x4)0.0f;

  for (int k0 = 0; k0 < K; k0 += 32) {
    __syncthreads();
#pragma unroll
    for (int it = 0; it < 2; ++it) {
      int chunk = it * 256 + tid;
      int row   = chunk >> 2;
      int cc    = chunk & 3;
      const u16* ga = A  + (size_t)(m0 + row) * K + k0 + cc * 8;
      const u16* gb = Bm + (size_t)(n0 + row) * K + k0 + cc * 8;
      char* la = (char*)Alds + (it * 256 + wave * 64) * 16;
      char* lb = (char*)Blds + (it * 256 + wave * 64) * 16;
      __builtin_amdgcn_global_load_lds((gas_ptr)ga, (las_ptr)la, 16, 0, 0);
      __builtin_amdgcn_global_load_lds((gas_ptr)gb, (las_ptr)lb, 16, 0, 0);
    }
    __syncthreads();

    bf16x8 a[4], b[4];
#pragma unroll
    for (int m = 0; m < 4; ++m)
      a[m] = *(const bf16x8*)(Alds + (wr * 64 + m * 16 + lr) * 32 + lg * 8);
#pragma unroll
    for (int n = 0; n < 4; ++n)
      b[n] = *(const bf16x8*)(Blds + (wc * 64 + n * 16 + lr) * 32 + lg * 8);
#pragma unroll
    for (int m = 0; m < 4; ++m)
#pragma unroll
      for (int n = 0; n < 4; ++n)
        acc[m][n] = __builtin_amdgcn_mfma_f32_16x16x32_bf16(a[m], b[n], acc[m][n], 0, 0, 0);
  }

#pragma unroll
  for (int m = 0; m < 4; ++m) {
    int grow = m0 + wr * 64 + m * 16 + lg * 4;
#pragma unroll
    for (int n = 0; n < 4; ++n) {
      int gcol = n0 + wc * 64 + n * 16 + lr;
#pragma unroll
      for (int r = 0; r < 4; ++r) {
        float val = acc[m][n][r];
        if (STORE_BF16) ((u16*)Cm)[(size_t)(grow + r) * N + gcol]   = f2bf(val);
        else            ((float*)Cm)[(size_t)(grow + r) * N + gcol] = val;
      }
    }
  }
}

// ---------------- RoPE (in-place on Q and K, bf16) ----------------
__global__ __launch_bounds__(256) void rope_kernel(u16* __restrict__ Q, u16* __restrict__ Kt){
  int gid  = blockIdx.x * 4 + (threadIdx.x >> 6);
  int lane = threadIdx.x & 63;
  int h = gid & (NH - 1);
  int s = (gid >> 4) & (SS - 1);
  int b = gid >> 15;
  size_t base = ((size_t)(b * SS + s)) * DIM + (size_t)h * HD;

  float ang = (float)s * __expf(-(float)lane * 0.14391156831212787f);
  float c, sn;
  sincosf(ang, &sn, &c);
  int jh = lane >> 1;
  int par = lane & 1;

  unsigned pq = *(const unsigned*)(Q + base + 2 * lane);
  float qe = bf2f((u16)(pq & 0xffff)), qo = bf2f((u16)(pq >> 16));
  float qa  = __shfl(qe, jh),      qb  = __shfl(qo, jh);
  float qa2 = __shfl(qe, 32 + jh), qb2 = __shfl(qo, 32 + jh);
  float qxj   = par ? qb  : qa;
  float qxj64 = par ? qb2 : qa2;
  u16 q_lo = f2bf(qxj   * c - qo * sn);
  u16 q_hi = f2bf(qxj64 * c + qe * sn);

  unsigned pk = *(const unsigned*)(Kt + base + 2 * lane);
  float ke = bf2f((u16)(pk & 0xffff)), ko = bf2f((u16)(pk >> 16));
  float ka  = __shfl(ke, jh),      kb  = __shfl(ko, jh);
  float ka2 = __shfl(ke, 32 + jh), kb2 = __shfl(ko, 32 + jh);
  float kxj   = par ? kb  : ka;
  float kxj64 = par ? kb2 : ka2;
  u16 k_lo = f2bf(kxj   * c - ko * sn);
  u16 k_hi = f2bf(kxj64 * c + ke * sn);

  Q [base + lane] = q_lo;  Q [base + 64 + lane] = q_hi;
  Kt[base + lane] = k_lo;  Kt[base + 64 + lane] = k_hi;
}

// ---------------- V transpose: V[b,s,h,d] -> VT[bh][d][s] ----------------
__global__ __launch_bounds__(256) void transpose_v(const u16* __restrict__ V,
                                                   u16* __restrict__ VT){
  __shared__ __align__(16) u16 T[64 * 64];
  const int tid = threadIdx.x;
  const int s0 = blockIdx.x * 64;
  const int d0 = blockIdx.y * 64;
  const int bh = blockIdx.z;
  const int b = bh >> 4, h = bh & 15;

#pragma unroll
  for (int it = 0; it < 2; ++it) {
    int c = it * 256 + tid;          // 512 chunks of 8 elems
    int s = c >> 3, cc = c & 7;
    uint4 v = *(const uint4*)(V + (size_t)(b * SS + s0 + s) * DIM + h * HD + d0 + cc * 8);
    *(uint4*)((char*)T + s * 128 + (((cc ^ (s & 7)) & 7) << 4)) = v;
  }
  __syncthreads();
#pragma unroll
  for (int it = 0; it < 2; ++it) {
    int c = it * 256 + tid;
    int d = c >> 3, sc = c & 7;
    u16 tmp[8];
#pragma unroll
    for (int j = 0; j < 8; ++j) {
      int s = sc * 8 + j;
      tmp[j] = *(const u16*)((char*)T + s * 128 + ((((d >> 3) ^ (s & 7)) & 7) << 4) + (d & 7) * 2);
    }
    *(uint4*)(VT + (size_t)bh * HD * SS + (size_t)(d0 + d) * SS + s0 + sc * 8) = *(const uint4*)tmp;
  }
}

// ---------------- Flash attention (causal), QBLK=128, 8 waves, KV tile 64 ----------------
// grid (8 pairs, 32 bh). Block handles q-tiles {p, 15-p} -> uniform 34 KV-iters.
// K,V double-buffered, staged via global_load_lds with pre-swizzled global source.
#define SCALE 0.08838834764831845f

__global__ __launch_bounds__(512) void attn_kernel(
    const u16* __restrict__ Q, const u16* __restrict__ Kg, const u16* __restrict__ VT,
    u16* __restrict__ AO)
{
  __shared__ __align__(16) u16 Klds[2][64 * 128];   // [kv][d], slot-swizzled
  __shared__ __align__(16) u16 Vlds[2][128 * 64];   // [d][kv], slot-swizzled
  __shared__ __align__(16) u16 Plds[8][16 * 64];

  const int tid  = threadIdx.x;
  const int lane = tid & 63;
  const int w    = tid >> 6;          // 0..7
  const int lg   = lane >> 4;
  const int lr   = lane & 15;
  const int pair = blockIdx.x;        // 0..7
  const int bh   = blockIdx.y;
  const int b    = bh >> 4, h = bh & 15;
  const size_t headoff = (size_t)b * SS * DIM + (size_t)h * HD;
  const u16* VTh = VT + (size_t)bh * HD * SS;

  for (int half = 0; half < 2; ++half) {
    const int Qt = half ? (15 - pair) : pair;
    const int qbase = Qt * 128;
    const int nkv = Qt * 2 + 2;

    // Q fragments: wave w owns rows qbase + w*16 + lr
    bf16x8 qf[4];
    {
      const u16* qrow = Q + headoff + (size_t)(qbase + w * 16 + lr) * DIM;
#pragma unroll
      for (int kf = 0; kf < 4; ++kf)
        qf[kf] = *(const bf16x8*)(qrow + kf * 32 + lg * 8);
    }

    f32x4 o_acc[8];
#pragma unroll
    for (int nf = 0; nf < 8; ++nf) o_acc[nf] = (f32x4)0.0f;
    float mrow[4] = {-INFINITY, -INFINITY, -INFINITY, -INFINITY};
    float lrow[4] = {0.f, 0.f, 0.f, 0.f};

    int cur = 0;

    // STAGE(buf, tile): 4 global_load_lds per thread (2 K + 2 V), swizzled source
#define STAGE(BUF, T)                                                              \
    {                                                                              \
      const int kv0s = (T) * 64;                                                   \
      _Pragma("unroll")                                                            \
      for (int it = 0; it < 2; ++it) {                                             \
        int c = it * 512 + tid;                                                    \
        int r = c >> 4, slot = c & 15;                                             \
        int cc = slot ^ (r & 7);                                                   \
        const u16* ga = Kg + headoff + (size_t)(kv0s + r) * DIM + cc * 8;          \
        char* la = (char*)Klds[BUF] + (it * 512 + w * 64) * 16;                    \
        __builtin_amdgcn_global_load_lds((gas_ptr)ga, (las_ptr)la, 16, 0, 0);      \
      }                                                                            \
      _Pragma("unroll")                                                            \
      for (int it = 0; it < 2; ++it) {                                             \
        int c = it * 512 + tid;                                                    \
        int d = c >> 3, slot = c & 7;                                              \
        int cc = slot ^ (d & 7);                                                   \
        const u16* gv = VTh + (size_t)d * SS + kv0s + cc * 8;                      \
        char* lv = (char*)Vlds[BUF] + (it * 512 + w * 64) * 16;                    \
        __builtin_amdgcn_global_load_lds((gas_ptr)gv, (las_ptr)lv, 16, 0, 0);      \
      }                                                                            \
    }

    STAGE(0, 0);
    __syncthreads();

    for (int t = 0; t < nkv; ++t) {
      const int kv0 = t * 64;
      if (t + 1 < nkv) STAGE(cur ^ 1, t + 1);

      if (kv0 <= qbase + w * 16 + 15) {   // wave-uniform: skip fully-masked waves
        // S = Q K^T : 16 q-rows x 64 kv
        f32x4 sacc[4];
#pragma unroll
        for (int sf = 0; sf < 4; ++sf) {
          sacc[sf] = (f32x4)0.0f;
          int row = sf * 16 + lr;
          int sw = row & 7;
#pragma unroll
          for (int kf = 0; kf < 4; ++kf) {
            int cc = kf * 4 + lg;
            bf16x8 kfrag = *(const bf16x8*)((char*)Klds[cur] + row * 256 + ((cc ^ sw) << 4));
            sacc[sf] = __builtin_amdgcn_mfma_f32_16x16x32_bf16(qf[kf], kfrag, sacc[sf], 0, 0, 0);
          }
        }

        // online softmax (rows = qbase + w*16 + lg*4 + r)
        float p[4][4];
        float mt[4];
#pragma unroll
        for (int r = 0; r < 4; ++r) {
          int qrow = qbase + w * 16 + lg * 4 + r;
          float mx = -INFINITY;
#pragma unroll
          for (int sf = 0; sf < 4; ++sf) {
            float v = sacc[sf][r] * SCALE;
            if (kv0 + sf * 16 + lr > qrow) v = -INFINITY;
            p[sf][r] = v;
            mx = fmaxf(mx, v);
          }
          mx = fmaxf(mx, __shfl_xor(mx, 1));
          mx = fmaxf(mx, __shfl_xor(mx, 2));
          mx = fmaxf(mx, __shfl_xor(mx, 4));
          mx = fmaxf(mx, __shfl_xor(mx, 8));
          mt[r] = mx;
        }
        float alpha[4];
#pragma unroll
        for (int r = 0; r < 4; ++r) {
          float mn = fmaxf(mrow[r], mt[r]);
          alpha[r] = __expf(mrow[r] - mn);
          mrow[r] = mn;
        }
#pragma unroll
        for (int r = 0; r < 4; ++r) {
          float s = 0.f;
#pragma unroll
          for (int sf = 0; sf < 4; ++sf) {
            float pv = __expf(p[sf][r] - mrow[r]);
            p[sf][r] = pv;
            s += pv;
          }
          s += __shfl_xor(s, 1);
          s += __shfl_xor(s, 2);
          s += __shfl_xor(s, 4);
          s += __shfl_xor(s, 8);
          lrow[r] = lrow[r] * alpha[r] + s;
        }
#pragma unroll
        for (int nf = 0; nf < 8; ++nf)
#pragma unroll
          for (int r = 0; r < 4; ++r) o_acc[nf][r] *= alpha[r];

        // P -> per-wave LDS (bf16, swizzled)
#pragma unroll
        for (int sf = 0; sf < 4; ++sf)
#pragma unroll
          for (int r = 0; r < 4; ++r) {
            int row = lg * 4 + r, col = sf * 16 + lr;
            int byteoff = (row * 128 + col * 2) ^ ((row & 7) << 4);
            *(u16*)((char*)Plds[w] + byteoff) = f2bf(p[sf][r]);
          }

        // O += P V
#pragma unroll
        for (int ks = 0; ks < 2; ++ks) {
          bf16x8 pfrag = *(const bf16x8*)((char*)Plds[w] + ((lr * 128 + ks * 64 + lg * 16) ^ ((lr & 7) << 4)));
#pragma unroll
          for (int nf = 0; nf < 8; ++nf) {
            int vrow = nf * 16 + lr;
            int cc = ks * 4 + lg;
            bf16x8 vfrag = *(const bf16x8*)((char*)Vlds[cur] + vrow * 128 + ((cc ^ (vrow & 7)) << 4));
            o_acc[nf] = __builtin_amdgcn_mfma_f32_16x16x32_bf16(pfrag, vfrag, o_acc[nf], 0, 0, 0);
          }
        }
      }

      __syncthreads();   // drains stage vmcnt + protects buffer swap
      cur ^= 1;
    }

    float inv[4];
#pragma unroll
    for (int r = 0; r < 4; ++r) inv[r] = 1.0f / lrow[r];
#pragma unroll
    for (int nf = 0; nf < 8; ++nf)
#pragma unroll
      for (int r = 0; r < 4; ++r) {
        int grow = qbase + w * 16 + lg * 4 + r;
        int col  = nf * 16 + lr;
        AO[(size_t)(b * SS + grow) * DIM + h * HD + col] = f2bf(o_acc[nf][r] * inv[r]);
      }
#undef STAGE
  }
}

// ---------------- launch ----------------
extern "C" void kernel_launch(void* const* d_in, const int* in_sizes, int n_in,
                              void* d_out, int out_size, void* d_ws, size_t ws_size,
                              hipStream_t stream)
{
  const float* x  = (const float*)d_in[0];
  const float* Wq = (const float*)d_in[1];
  const float* Wk = (const float*)d_in[2];
  const float* Wv = (const float*)d_in[3];
  const float* Wo = (const float*)d_in[4];
  float* out = (float*)d_out;

  char* ws = (char*)d_ws;
  const size_t XB_BYTES = (size_t)MTOT * DIM * 2;   // 16 MB
  const size_t W_BYTES  = (size_t)DIM * DIM * 2;    // 8 MB
  u16* xb = (u16*)ws;                                // x bf16; later reused as AO
  u16* w0 = (u16*)(ws + XB_BYTES);                   // Wq, later Wo
  u16* w1 = (u16*)(ws + XB_BYTES + W_BYTES);         // Wk, later VT (spans w1+w2)
  u16* w2 = (u16*)(ws + XB_BYTES + 2 * W_BYTES);     // Wv
  u16* Qb = (u16*)(ws + XB_BYTES + 3 * W_BYTES);
  u16* Kb = Qb + (size_t)MTOT * DIM;
  u16* Vb = Kb + (size_t)MTOT * DIM;
  u16* AO = xb;
  u16* VTb = w1;                                     // 16 MB (w1+w2), free after QKV GEMM

  cvt_kernel<<<8192, 256, 0, stream>>>(x,  xb, 2097152);
  cvt_kernel<<<4096, 256, 0, stream>>>(Wq, w0, 1048576);
  cvt_kernel<<<4096, 256, 0, stream>>>(Wk, w1, 1048576);
  cvt_kernel<<<4096, 256, 0, stream>>>(Wv, w2, 1048576);

  gemm_bt<true><<<dim3(16, 32, 3), 256, 0, stream>>>(xb, w0, w1, w2,
                                                     (void*)Qb, (void*)Kb, (void*)Vb,
                                                     MTOT, DIM, DIM);

  transpose_v<<<dim3(32, 2, 32), 256, 0, stream>>>(Vb, VTb);

  rope_kernel<<<16384, 256, 0, stream>>>(Qb, Kb);

  cvt_kernel<<<4096, 256, 0, stream>>>(Wo, w0, 1048576);  // Wq slot no longer needed

  attn_kernel<<<dim3(8, 32), 512, 0, stream>>>(Qb, Kb, VTb, AO);

  gemm_bt<false><<<dim3(16, 32, 1), 256, 0, stream>>>(AO, w0, w0, w0,
                                                      (void*)out, (void*)out, (void*)out,
                                                      MTOT, DIM, DIM);
}